// Round 7
// baseline (1499.466 us; speedup 1.0000x reference)
//
#include <hip/hip_runtime.h>
#include <cstdint>
#include <cstddef>

#define B_ 4096
#define T_ 128
#define N_ 128
#define H_ 128
#define G4_ 512       // 4*H
#define KC_ 256       // concat K = [x|h]
#define EPS_ 1e-5f

#define RPB_ 16       // batch rows per block (k4)
#define NB_ 256       // k4 blocks (one per CU)
#define W0K_ 128      // layer0 K-half staged in LDS (k = 0..127, the x-part)
#define W0P_ 136      // W0l LDS stride (f16)

#define KB2_ 256      // k12 blocks (one per CU)
#define ROWS2_ 16     // b-rows per k12 block

typedef _Float16 f16x8 __attribute__((ext_vector_type(8)));
typedef _Float16 f16x4 __attribute__((ext_vector_type(4)));
typedef float f32x4 __attribute__((ext_vector_type(4)));

__device__ __forceinline__ float sigm_(float x) { return 1.f / (1.f + __expf(-x)); }
__device__ __forceinline__ float tanh_(float x) {
  float ax = fabsf(x);
  float e = __expf(-2.f * ax);
  float t = (1.f - e) / (1.f + e);
  return copysignf(t, x);
}

#define MFMA16(a, b, c) __builtin_amdgcn_mfma_f32_16x16x32_f16((a), (b), (c), 0, 0, 0)

// ---------------- K0: pack weights to f16 [2][512][256] = [Wih | Whh], combine biases
__global__ void k0_prep(const float* __restrict__ Wih0, const float* __restrict__ Whh0,
                        const float* __restrict__ bih0, const float* __restrict__ bhh0,
                        const float* __restrict__ Wih1, const float* __restrict__ Whh1,
                        const float* __restrict__ bih1, const float* __restrict__ bhh1,
                        _Float16* __restrict__ Wpack, float* __restrict__ bpack) {
  int idx = blockIdx.x * blockDim.x + threadIdx.x;
  if (idx < 2 * G4_ * KC_) {
    int k = idx & (KC_ - 1);
    int j = (idx >> 8) & (G4_ - 1);
    int l = idx >> 17;
    const float* Wih = l ? Wih1 : Wih0;
    const float* Whh = l ? Whh1 : Whh0;
    float v = (k < N_) ? Wih[j * N_ + k] : Whh[j * N_ + (k - N_)];
    Wpack[idx] = (_Float16)v;
  }
  if (idx < 2 * G4_) {
    int j = idx & (G4_ - 1);
    bpack[idx] = (idx >> 9) ? (bih1[j] + bhh1[j]) : (bih0[j] + bhh0[j]);
  }
}

// ---------------- K12: fused alpha + X_tilde + BN partials, double-buffered (round-6)
__global__ __launch_bounds__(512, 1) void k12_fused(
    const float* __restrict__ X, const float* __restrict__ attn_w,
    const float* __restrict__ attn_b, float* __restrict__ out0,
    float* __restrict__ psum, float* __restrict__ psq) {
  __shared__ float xs[2 * T_ * N_];  // 131072 B
  __shared__ float wx[T_];
  __shared__ float redS[4][N_];
  __shared__ float redM[8], redE[8];
  const int tid = threadIdx.x;   // 0..511
  const int blk = blockIdx.x;    // 0..255
  const int n = tid & 127;
  const int tq = tid >> 7;       // t-quarter 0..3
  const int wv = tid >> 6;       // wave 0..7
  const int row0 = blk * ROWS2_;
  if (tid < T_) wx[tid] = attn_w[2 * H_ + tid];
  const float ab = attn_b[0];

  float sum[32], sq[32];
#pragma unroll
  for (int i = 0; i < 32; ++i) { sum[i] = 0.f; sq[i] = 0.f; }

  {
    const float* xb = X + (size_t)row0 * T_ * N_;
#pragma unroll
    for (int i = 0; i < 8; ++i) {
      int fi = ((i << 9) + tid) << 2;
      *(f32x4*)&xs[fi] = *(const f32x4*)&xb[fi];
    }
  }

  int buf = 0;
  for (int rb = 0; rb < ROWS2_; ++rb) {
    __syncthreads();
    const float* xcur = xs + (buf << 14);

    f32x4 stg[8];
    if (rb + 1 < ROWS2_) {
      const float* xb1 = X + (size_t)(row0 + rb + 1) * T_ * N_;
#pragma unroll
      for (int i = 0; i < 8; ++i)
        stg[i] = *(const f32x4*)&xb1[((i << 9) + tid) << 2];
    }

    float s = 0.f;
#pragma unroll
    for (int tt = 0; tt < 32; ++tt) {
      int t = (tq << 5) + tt;
      s = fmaf(xcur[t * N_ + n], wx[t], s);
    }
    redS[tq][n] = s;
    __syncthreads();
    s = redS[0][n] + redS[1][n] + redS[2][n] + redS[3][n] + ab;

    float m = s;
#pragma unroll
    for (int off = 32; off >= 1; off >>= 1) m = fmaxf(m, __shfl_xor(m, off));
    if ((tid & 63) == 0) redM[wv] = m;
    __syncthreads();
    m = fmaxf(fmaxf(fmaxf(redM[0], redM[1]), fmaxf(redM[2], redM[3])),
              fmaxf(fmaxf(redM[4], redM[5]), fmaxf(redM[6], redM[7])));
    float e = __expf(s - m);
    float sm = e;
#pragma unroll
    for (int off = 32; off >= 1; off >>= 1) sm += __shfl_xor(sm, off);
    if ((tid & 63) == 0) redE[wv] = sm;
    __syncthreads();
    sm = redE[0] + redE[1];
    const float alpha = e / sm;

    if (rb + 1 < ROWS2_) {
      float* xnx = xs + ((buf ^ 1) << 14);
#pragma unroll
      for (int i = 0; i < 8; ++i)
        *(f32x4*)&xnx[((i << 9) + tid) << 2] = stg[i];
    }

    const size_t b = (size_t)(row0 + rb);
#pragma unroll
    for (int tt = 0; tt < 32; ++tt) {
      int t = (tq << 5) + tt;
      float v = alpha * xcur[t * N_ + n];
      sum[tt] += v;
      sq[tt] += v * v;
      out0[(b * T_ + t) * N_ + n] = v;
    }
    buf ^= 1;
  }

  float* pbs = psum + ((size_t)blk << 14) + (tq << 5) * N_ + n;
  float* pbq = psq + ((size_t)blk << 14) + (tq << 5) * N_ + n;
#pragma unroll
  for (int tt = 0; tt < 32; ++tt) {
    pbs[tt * N_] = sum[tt];
    pbq[tt * N_] = sq[tt];
  }
}

// ---------------- K3r: reduce partials over 256 blocks -> per-(t,n) scale/shift
__global__ void k3r(const float* __restrict__ psum, const float* __restrict__ psq,
                    const float* __restrict__ gamma, const float* __restrict__ beta,
                    float* __restrict__ scale, float* __restrict__ shift) {
  __shared__ float rs[2][N_], rq[2][N_];
  const int t = blockIdx.x;     // 0..127
  const int tid = threadIdx.x;  // 0..255
  const int n = tid & 127;
  const int hb = tid >> 7;
  const size_t off = (size_t)t * N_ + n;
  float s = 0.f, q = 0.f;
#pragma unroll 4
  for (int i = 0; i < 128; ++i) {
    size_t o = ((size_t)((hb << 7) + i) << 14) + off;
    s += psum[o];
    q += psq[o];
  }
  rs[hb][n] = s;
  rq[hb][n] = q;
  __syncthreads();
  if (hb == 0) {
    s = rs[0][n] + rs[1][n];
    q = rq[0][n] + rq[1][n];
    float mean = s * (1.f / B_);
    float var = q * (1.f / B_) - mean * mean;
    float rstd = rsqrtf(var + EPS_);
    float g = gamma[n];
    scale[t * N_ + n] = rstd * g;
    shift[t * N_ + n] = beta[n] - mean * rstd * g;
  }
}

// ---------------- K4 v8: software-pipelined recurrence — 2 barriers/step.
// Iteration t runs GEMM1(t) and GEMM0(t+1) in ONE barrier-free region (both enabled
// once h0(t) is in LDS), then merged act1(t)+act0(t+1), then {write h's, stage xb},
// then barrier. Halves barrier count vs v2 and doubles the MFMA/load-pipelining
// window. All v2-proven idioms kept: plain remat-friendly w1 loads, inline W0h
// stream, single-buffered A-tiles (R1 = LDS-read-only, R2 = LDS-write-only).
__global__ __launch_bounds__(512, 2) void k4_recur(
    const float* __restrict__ xt /* X_tilde */, const _Float16* __restrict__ Wpack,
    const float* __restrict__ bpack, const float* __restrict__ scale,
    const float* __restrict__ shift, float* __restrict__ out1) {
  __shared__ _Float16 W0l[G4_][W0P_];  // 139264 B
  __shared__ _Float16 A0[RPB_][264];   // [xb(t+1) | h0(t)]
  __shared__ _Float16 A1[RPB_][264];   // [h0n(t)  | h1(t-1)]   (total 156160 B)

  const int tid = threadIdx.x;
  const int w = tid >> 6;
  const int lane = tid & 63;
  const int quad = lane >> 4;
  const int l16 = lane & 15;
  const int nb = blockIdx.x;
  const int col = (w << 4) + l16;

  {
    const _Float16* src = Wpack + (size_t)tid * KC_;
#pragma unroll
    for (int kk = 0; kk < W0K_; kk += 8)
      *(f16x8*)&W0l[tid][kk] = *(const f16x8*)&src[kk];
  }

  f16x8 w1[4][8];
#pragma unroll
  for (int g = 0; g < 4; ++g) {
    const _Float16* src = Wpack + (size_t)(G4_ + (g << 7) + col) * KC_ + (quad << 3);
#pragma unroll
    for (int kb = 0; kb < 8; ++kb) w1[g][kb] = *(const f16x8*)&src[kb << 5];
  }

  float bia0[4], bia1[4];
#pragma unroll
  for (int g = 0; g < 4; ++g) {
    bia0[g] = bpack[(g << 7) + col];
    bia1[g] = bpack[G4_ + (g << 7) + col];
  }

  float c0[4], c1[4];
#pragma unroll
  for (int e = 0; e < 4; ++e) { c0[e] = 0.f; c1[e] = 0.f; }

  const int sr = tid >> 5;
  const int sc = (tid & 31) << 2;
  const size_t browbase = (size_t)(nb * RPB_ + sr) * T_;
  const size_t orowbase = (size_t)(nb * RPB_ + (quad << 2)) * T_;

  // ---- prologue: xb(0), zero h-halves
  {
    f32x4 xv = *(const f32x4*)(xt + (browbase + 0) * N_ + sc);
    f32x4 s4 = *(const f32x4*)(scale + sc);
    f32x4 h4 = *(const f32x4*)(shift + sc);
    f16x4 hv;
#pragma unroll
    for (int e = 0; e < 4; ++e) hv[e] = (_Float16)fmaf(xv[e], s4[e], h4[e]);
    *(f16x4*)&A0[sr][sc] = hv;
    f16x4 z = {};
    *(f16x4*)&A0[sr][N_ + sc] = z;
    *(f16x4*)&A1[sr][N_ + sc] = z;
  }
  __syncthreads();

  // ---- prologue GEMM0(0): [xb(0)|0] @ W0^T -> h0n(0)
  {
    f32x4 acc[4] = {};
#pragma unroll
    for (int kb = 0; kb < 8; ++kb) {
      f16x8 a = *(const f16x8*)&A0[l16][(kb << 5) + (quad << 3)];
      if (kb < 4) {
#pragma unroll
        for (int g = 0; g < 4; ++g) {
          f16x8 bf = *(const f16x8*)&W0l[(g << 7) + col][(kb << 5) + (quad << 3)];
          acc[g] = MFMA16(a, bf, acc[g]);
        }
      } else {
#pragma unroll
        for (int g = 0; g < 4; ++g) {
          f16x8 bf = *(const f16x8*)(Wpack + (size_t)((g << 7) + col) * KC_ +
                                     (kb << 5) + (quad << 3));
          acc[g] = MFMA16(a, bf, acc[g]);
        }
      }
    }
    _Float16 h0h[4];
#pragma unroll
    for (int e = 0; e < 4; ++e) {
      float ig = acc[0][e] + bia0[0];
      float fg = acc[1][e] + bia0[1];
      float gg = acc[2][e] + bia0[2];
      float og = acc[3][e] + bia0[3];
      float cn = sigm_(fg) * c0[e] + sigm_(ig) * tanh_(gg);
      c0[e] = cn;
      h0h[e] = (_Float16)(sigm_(og) * tanh_(cn));
    }
    __syncthreads();  // GEMM0(0)'s A0 reads complete
#pragma unroll
    for (int e = 0; e < 4; ++e) {
      A1[(quad << 2) + e][col] = h0h[e];        // h0n(0) for GEMM1(0)
      A0[(quad << 2) + e][N_ + col] = h0h[e];   // h0(0) for GEMM0(1)
    }
    {  // stage xb(1)
      f32x4 xv = *(const f32x4*)(xt + (browbase + 1) * N_ + sc);
      f32x4 s4 = *(const f32x4*)(scale + 1 * N_ + sc);
      f32x4 h4 = *(const f32x4*)(shift + 1 * N_ + sc);
      f16x4 hv;
#pragma unroll
      for (int e = 0; e < 4; ++e) hv[e] = (_Float16)fmaf(xv[e], s4[e], h4[e]);
      *(f16x4*)&A0[sr][sc] = hv;
    }
    __syncthreads();
  }

  // ---- main loop: t = 0..126, each iter = GEMM1(t) + GEMM0(t+1), 2 barriers
  for (int t = 0; t < T_ - 1; ++t) {
    // prefetch x/scale/shift (t+2)
    f32x4 xn = {}, scn = {}, shn = {};
    if (t + 2 < T_) {
      xn = *(const f32x4*)(xt + (browbase + t + 2) * N_ + sc);
      scn = *(const f32x4*)(scale + (t + 2) * N_ + sc);
      shn = *(const f32x4*)(shift + (t + 2) * N_ + sc);
    }

    // -- GEMM1(t): [h0n(t)|h1(t-1)] @ W1^T (w1 remat from L2, compiler-pipelined)
    f16x8 a1[8];
#pragma unroll
    for (int kb = 0; kb < 4; ++kb) {
      a1[kb] = *(const f16x8*)&A1[l16][(kb << 5) + (quad << 3)];
      a1[4 + kb] = *(const f16x8*)&A1[l16][128 + (kb << 5) + (quad << 3)];
    }
    f32x4 acc1[4] = {};
#pragma unroll
    for (int kb = 0; kb < 8; ++kb) {
#pragma unroll
      for (int g = 0; g < 4; ++g) acc1[g] = MFMA16(a1[kb], w1[g][kb], acc1[g]);
    }

    // -- GEMM0(t+1): [xb(t+1)|h0(t)] @ W0^T (kb0-3 LDS, kb4-7 L2 stream)
    f32x4 acc[4] = {};
#pragma unroll
    for (int kb = 0; kb < 8; ++kb) {
      f16x8 a = *(const f16x8*)&A0[l16][(kb << 5) + (quad << 3)];
      if (kb < 4) {
#pragma unroll
        for (int g = 0; g < 4; ++g) {
          f16x8 bf = *(const f16x8*)&W0l[(g << 7) + col][(kb << 5) + (quad << 3)];
          acc[g] = MFMA16(a, bf, acc[g]);
        }
      } else {
#pragma unroll
        for (int g = 0; g < 4; ++g) {
          f16x8 bf = *(const f16x8*)(Wpack + (size_t)((g << 7) + col) * KC_ +
                                     (kb << 5) + (quad << 3));
          acc[g] = MFMA16(a, bf, acc[g]);
        }
      }
    }

    // -- act1(t): c1/h1, store out1(t)
    _Float16 h1h[4];
#pragma unroll
    for (int e = 0; e < 4; ++e) {
      float ig = acc1[0][e] + bia1[0];
      float fg = acc1[1][e] + bia1[1];
      float gg = acc1[2][e] + bia1[2];
      float og = acc1[3][e] + bia1[3];
      float cn = sigm_(fg) * c1[e] + sigm_(ig) * tanh_(gg);
      c1[e] = cn;
      float hn = sigm_(og) * tanh_(cn);
      h1h[e] = (_Float16)hn;
      out1[(orowbase + (size_t)e * T_ + t) * H_ + col] = hn;
    }
    // -- act0(t+1): c0/h0 (independent chain)
    _Float16 h0h[4];
#pragma unroll
    for (int e = 0; e < 4; ++e) {
      float ig = acc[0][e] + bia0[0];
      float fg = acc[1][e] + bia0[1];
      float gg = acc[2][e] + bia0[2];
      float og = acc[3][e] + bia0[3];
      float cn = sigm_(fg) * c0[e] + sigm_(ig) * tanh_(gg);
      c0[e] = cn;
      h0h[e] = (_Float16)(sigm_(og) * tanh_(cn));
    }
    __syncthreads();  // mid: all A0/A1 reads of this iter complete
#pragma unroll
    for (int e = 0; e < 4; ++e) {
      A1[(quad << 2) + e][col] = h0h[e];        // h0n(t+1) -> GEMM1(t+1)
      A1[(quad << 2) + e][N_ + col] = h1h[e];   // h1(t)    -> GEMM1(t+1)
      A0[(quad << 2) + e][N_ + col] = h0h[e];   // h0(t+1)  -> GEMM0(t+2)
    }
    if (t + 2 < T_) {  // xb(t+2) -> GEMM0(t+2)
      f16x4 hv;
#pragma unroll
      for (int e = 0; e < 4; ++e) hv[e] = (_Float16)fmaf(xn[e], scn[e], shn[e]);
      *(f16x4*)&A0[sr][sc] = hv;
    }
    __syncthreads();  // end: tiles ready for next iter
  }

  // ---- epilogue: GEMM1(127) + act1 + store
  {
    f16x8 a1[8];
#pragma unroll
    for (int kb = 0; kb < 4; ++kb) {
      a1[kb] = *(const f16x8*)&A1[l16][(kb << 5) + (quad << 3)];
      a1[4 + kb] = *(const f16x8*)&A1[l16][128 + (kb << 5) + (quad << 3)];
    }
    f32x4 acc1[4] = {};
#pragma unroll
    for (int kb = 0; kb < 8; ++kb) {
#pragma unroll
      for (int g = 0; g < 4; ++g) acc1[g] = MFMA16(a1[kb], w1[g][kb], acc1[g]);
    }
#pragma unroll
    for (int e = 0; e < 4; ++e) {
      float ig = acc1[0][e] + bia1[0];
      float fg = acc1[1][e] + bia1[1];
      float gg = acc1[2][e] + bia1[2];
      float og = acc1[3][e] + bia1[3];
      float cn = sigm_(fg) * c1[e] + sigm_(ig) * tanh_(gg);
      float hn = sigm_(og) * tanh_(cn);
      out1[(orowbase + (size_t)e * T_ + (T_ - 1)) * H_ + col] = hn;
    }
  }
}

extern "C" void kernel_launch(void* const* d_in, const int* in_sizes, int n_in,
                              void* d_out, int out_size, void* d_ws, size_t ws_size,
                              hipStream_t stream) {
  const float* X = (const float*)d_in[0];
  const float* attnw = (const float*)d_in[1];
  const float* attnb = (const float*)d_in[2];
  const float* gamma = (const float*)d_in[3];
  const float* beta = (const float*)d_in[4];
  const float* Wih0 = (const float*)d_in[5];
  const float* Whh0 = (const float*)d_in[6];
  const float* bih0 = (const float*)d_in[7];
  const float* bhh0 = (const float*)d_in[8];
  const float* Wih1 = (const float*)d_in[9];
  const float* Whh1 = (const float*)d_in[10];
  const float* bih1 = (const float*)d_in[11];
  const float* bhh1 = (const float*)d_in[12];

  float* out0 = (float*)d_out;                    // X_tilde
  float* out1 = out0 + (size_t)B_ * T_ * N_;      // X_encoded

  // BN partials use out1's region as scratch; consumed by k3r before k4 writes out1.
  float* psum = out1;
  float* psq = out1 + ((size_t)KB2_ << 14);

  float* ws = (float*)d_ws;
  float* scale = ws;                              // T*N
  float* shift = scale + T_ * N_;                 // T*N
  float* bpack = shift + T_ * N_;                 // 2*512
  _Float16* Wpack = (_Float16*)(bpack + 2 * G4_); // 2*512*256 f16 (16B-aligned)

  k0_prep<<<1024, 256, 0, stream>>>(Wih0, Whh0, bih0, bhh0, Wih1, Whh1, bih1, bhh1,
                                    Wpack, bpack);
  k12_fused<<<KB2_, 512, 0, stream>>>(X, attnw, attnb, out0, psum, psq);
  k3r<<<T_, 256, 0, stream>>>(psum, psq, gamma, beta, scale, shift);
  k4_recur<<<NB_, 512, 0, stream>>>(out0, Wpack, bpack, scale, shift, out1);
}

// Round 8
// 1355.373 us; speedup vs baseline: 1.1063x; 1.1063x over previous
//
#include <hip/hip_runtime.h>
#include <cstdint>
#include <cstddef>

#define B_ 4096
#define T_ 128
#define N_ 128
#define H_ 128
#define G4_ 512       // 4*H
#define KC_ 256       // concat K = [x|h]
#define EPS_ 1e-5f

#define RPB_ 16       // batch rows per block (k4)
#define NB_ 256       // k4 blocks (one per CU)
#define W0K_ 128      // layer0 K-half staged in LDS (k = 0..127, the x-part)
#define AP_ 136       // A-tile LDS stride (f16): 272 B

#define KB2_ 256      // k12 blocks (one per CU)
#define ROWS2_ 16     // b-rows per k12 block

typedef _Float16 f16x8 __attribute__((ext_vector_type(8)));
typedef _Float16 f16x4 __attribute__((ext_vector_type(4)));
typedef float f32x4 __attribute__((ext_vector_type(4)));

__device__ __forceinline__ float sigm_(float x) { return 1.f / (1.f + __expf(-x)); }
__device__ __forceinline__ float tanh_(float x) {
  float ax = fabsf(x);
  float e = __expf(-2.f * ax);
  float t = (1.f - e) / (1.f + e);
  return copysignf(t, x);
}

#define MFMA16(a, b, c) __builtin_amdgcn_mfma_f32_16x16x32_f16((a), (b), (c), 0, 0, 0)

// ---------------- K0: pack weights to f16 [2][512][256] = [Wih | Whh], combine biases
__global__ void k0_prep(const float* __restrict__ Wih0, const float* __restrict__ Whh0,
                        const float* __restrict__ bih0, const float* __restrict__ bhh0,
                        const float* __restrict__ Wih1, const float* __restrict__ Whh1,
                        const float* __restrict__ bih1, const float* __restrict__ bhh1,
                        _Float16* __restrict__ Wpack, float* __restrict__ bpack) {
  int idx = blockIdx.x * blockDim.x + threadIdx.x;
  if (idx < 2 * G4_ * KC_) {
    int k = idx & (KC_ - 1);
    int j = (idx >> 8) & (G4_ - 1);
    int l = idx >> 17;
    const float* Wih = l ? Wih1 : Wih0;
    const float* Whh = l ? Whh1 : Whh0;
    float v = (k < N_) ? Wih[j * N_ + k] : Whh[j * N_ + (k - N_)];
    Wpack[idx] = (_Float16)v;
  }
  if (idx < 2 * G4_) {
    int j = idx & (G4_ - 1);
    bpack[idx] = (idx >> 9) ? (bih1[j] + bhh1[j]) : (bih0[j] + bhh0[j]);
  }
}

// ---------------- K12: fused alpha + X_tilde + BN partials, double-buffered (round-6, proven)
__global__ __launch_bounds__(512, 1) void k12_fused(
    const float* __restrict__ X, const float* __restrict__ attn_w,
    const float* __restrict__ attn_b, float* __restrict__ out0,
    float* __restrict__ psum, float* __restrict__ psq) {
  __shared__ float xs[2 * T_ * N_];  // 131072 B
  __shared__ float wx[T_];
  __shared__ float redS[4][N_];
  __shared__ float redM[8], redE[8];
  const int tid = threadIdx.x;   // 0..511
  const int blk = blockIdx.x;    // 0..255
  const int n = tid & 127;
  const int tq = tid >> 7;       // t-quarter 0..3
  const int wv = tid >> 6;       // wave 0..7
  const int row0 = blk * ROWS2_;
  if (tid < T_) wx[tid] = attn_w[2 * H_ + tid];
  const float ab = attn_b[0];

  float sum[32], sq[32];
#pragma unroll
  for (int i = 0; i < 32; ++i) { sum[i] = 0.f; sq[i] = 0.f; }

  {
    const float* xb = X + (size_t)row0 * T_ * N_;
#pragma unroll
    for (int i = 0; i < 8; ++i) {
      int fi = ((i << 9) + tid) << 2;
      *(f32x4*)&xs[fi] = *(const f32x4*)&xb[fi];
    }
  }

  int buf = 0;
  for (int rb = 0; rb < ROWS2_; ++rb) {
    __syncthreads();
    const float* xcur = xs + (buf << 14);

    f32x4 stg[8];
    if (rb + 1 < ROWS2_) {
      const float* xb1 = X + (size_t)(row0 + rb + 1) * T_ * N_;
#pragma unroll
      for (int i = 0; i < 8; ++i)
        stg[i] = *(const f32x4*)&xb1[((i << 9) + tid) << 2];
    }

    float s = 0.f;
#pragma unroll
    for (int tt = 0; tt < 32; ++tt) {
      int t = (tq << 5) + tt;
      s = fmaf(xcur[t * N_ + n], wx[t], s);
    }
    redS[tq][n] = s;
    __syncthreads();
    s = redS[0][n] + redS[1][n] + redS[2][n] + redS[3][n] + ab;

    float m = s;
#pragma unroll
    for (int off = 32; off >= 1; off >>= 1) m = fmaxf(m, __shfl_xor(m, off));
    if ((tid & 63) == 0) redM[wv] = m;
    __syncthreads();
    m = fmaxf(fmaxf(fmaxf(redM[0], redM[1]), fmaxf(redM[2], redM[3])),
              fmaxf(fmaxf(redM[4], redM[5]), fmaxf(redM[6], redM[7])));
    float e = __expf(s - m);
    float sm = e;
#pragma unroll
    for (int off = 32; off >= 1; off >>= 1) sm += __shfl_xor(sm, off);
    if ((tid & 63) == 0) redE[wv] = sm;
    __syncthreads();
    sm = redE[0] + redE[1];
    const float alpha = e / sm;

    if (rb + 1 < ROWS2_) {
      float* xnx = xs + ((buf ^ 1) << 14);
#pragma unroll
      for (int i = 0; i < 8; ++i)
        *(f32x4*)&xnx[((i << 9) + tid) << 2] = stg[i];
    }

    const size_t b = (size_t)(row0 + rb);
#pragma unroll
    for (int tt = 0; tt < 32; ++tt) {
      int t = (tq << 5) + tt;
      float v = alpha * xcur[t * N_ + n];
      sum[tt] += v;
      sq[tt] += v * v;
      out0[(b * T_ + t) * N_ + n] = v;
    }
    buf ^= 1;
  }

  float* pbs = psum + ((size_t)blk << 14) + (tq << 5) * N_ + n;
  float* pbq = psq + ((size_t)blk << 14) + (tq << 5) * N_ + n;
#pragma unroll
  for (int tt = 0; tt < 32; ++tt) {
    pbs[tt * N_] = sum[tt];
    pbq[tt * N_] = sq[tt];
  }
}

// ---------------- K3r: reduce partials over 256 blocks -> per-(t,n) scale/shift
__global__ void k3r(const float* __restrict__ psum, const float* __restrict__ psq,
                    const float* __restrict__ gamma, const float* __restrict__ beta,
                    float* __restrict__ scale, float* __restrict__ shift) {
  __shared__ float rs[2][N_], rq[2][N_];
  const int t = blockIdx.x;     // 0..127
  const int tid = threadIdx.x;  // 0..255
  const int n = tid & 127;
  const int hb = tid >> 7;
  const size_t off = (size_t)t * N_ + n;
  float s = 0.f, q = 0.f;
#pragma unroll 4
  for (int i = 0; i < 128; ++i) {
    size_t o = ((size_t)((hb << 7) + i) << 14) + off;
    s += psum[o];
    q += psq[o];
  }
  rs[hb][n] = s;
  rq[hb][n] = q;
  __syncthreads();
  if (hb == 0) {
    s = rs[0][n] + rs[1][n];
    q = rq[0][n] + rq[1][n];
    float mean = s * (1.f / B_);
    float var = q * (1.f / B_) - mean * mean;
    float rstd = rsqrtf(var + EPS_);
    float g = gamma[n];
    scale[t * N_ + n] = rstd * g;
    shift[t * N_ + n] = beta[n] - mean * rstd * g;
  }
}

// ---------------- K4 v9: v6 GEMM code verbatim; schedule = 2 barriers/step via
// h-tile double-buffering + act1 deferred one step (overlaps GEMM0(t+1)'s MFMAs).
// Region-A: act1(t-1) || GEMM0(t) -> act0 -> write h0n/h0.  b-mid.
// Region-B: GEMM1(t) (w1 remat untouched) + stage xb(t+1).  b-end.
// LDS: swizzled W0l (stride 128, v3-proven) + XB + H0[2] + H0n + H1 = 152832 B.
__global__ __launch_bounds__(512, 2) void k4_recur(
    const float* __restrict__ xt /* X_tilde */, const _Float16* __restrict__ Wpack,
    const float* __restrict__ bpack, const float* __restrict__ scale,
    const float* __restrict__ shift, float* __restrict__ out1) {
  __shared__ _Float16 W0l[G4_ * 128];   // 131072 B, XOR-swizzled 256 B rows
  __shared__ _Float16 XB[RPB_][AP_];    // xb(t)                 4352 B
  __shared__ _Float16 H0[2][RPB_][AP_]; // h0 (double-buffered)  8704 B
  __shared__ _Float16 H0n[RPB_][AP_];   // h0n(t) -> GEMM1 in    4352 B
  __shared__ _Float16 H1[RPB_][AP_];    // h1(t-1) -> GEMM1 in   4352 B

  const int tid = threadIdx.x;
  const int w = tid >> 6;
  const int lane = tid & 63;
  const int quad = lane >> 4;
  const int l16 = lane & 15;
  const int nb = blockIdx.x;
  const int col = (w << 4) + l16;

  // ---- one-time: stage W0 x-half into LDS, swizzled (row r: byte ^= (r&7)<<4)
  {
    const _Float16* src = Wpack + (size_t)tid * KC_;
    char* dst = (char*)W0l + tid * 256;
    const int sw = (tid & 7) << 4;
#pragma unroll
    for (int o = 0; o < 256; o += 16)
      *(f16x8*)(dst + (o ^ sw)) = *(const f16x8*)((const char*)src + o);
  }

  // layer-1 weights: plain loads (compiler remats/pipelines from L2 — v2/v6-proven)
  f16x8 w1[4][8];
#pragma unroll
  for (int g = 0; g < 4; ++g) {
    const _Float16* src = Wpack + (size_t)(G4_ + (g << 7) + col) * KC_ + (quad << 3);
#pragma unroll
    for (int kb = 0; kb < 8; ++kb) w1[g][kb] = *(const f16x8*)&src[kb << 5];
  }

  float bia0[4], bia1[4];
#pragma unroll
  for (int g = 0; g < 4; ++g) {
    bia0[g] = bpack[(g << 7) + col];
    bia1[g] = bpack[G4_ + (g << 7) + col];
  }

  float c0[4], c1[4];
#pragma unroll
  for (int e = 0; e < 4; ++e) { c0[e] = 0.f; c1[e] = 0.f; }
  f32x4 acc1[4] = {};  // carried: GEMM1(t) result, activated in region-A(t+1)

  const int sr = tid >> 5;
  const int sc = (tid & 31) << 2;
  const size_t browbase = (size_t)(nb * RPB_ + sr) * T_;
  const size_t orowbase = (size_t)(nb * RPB_ + (quad << 2)) * T_;
  const int swr = (l16 & 7) << 4;  // W0l read-side swizzle (row&7 == l16&7)

  // ---- prologue: stage xb(0), zero h-buffers
  {
    f32x4 xv = *(const f32x4*)(xt + (browbase + 0) * N_ + sc);
    f32x4 s4 = *(const f32x4*)(scale + sc);
    f32x4 h4 = *(const f32x4*)(shift + sc);
    f16x4 hv;
#pragma unroll
    for (int e = 0; e < 4; ++e) hv[e] = (_Float16)fmaf(xv[e], s4[e], h4[e]);
    *(f16x4*)&XB[sr][sc] = hv;
    f16x4 z = {};
    *(f16x4*)&H0[0][sr][sc] = z;
    *(f16x4*)&H1[sr][sc] = z;
  }
  __syncthreads();

  for (int t = 0; t < T_; ++t) {
    const int cb = t & 1, cbn = cb ^ 1;

    // prefetch xb(t+1) inputs (consumed in region-B staging)
    f32x4 xn = {}, scn = {}, shn = {};
    if (t + 1 < T_) {
      xn = *(const f32x4*)(xt + (browbase + t + 1) * N_ + sc);
      scn = *(const f32x4*)(scale + (t + 1) * N_ + sc);
      shn = *(const f32x4*)(shift + (t + 1) * N_ + sc);
    }

    // ---- deferred act1(t-1): VALU-only, overlaps GEMM0(t)'s MFMA pipe
    if (t > 0) {
      _Float16 h1h[4];
#pragma unroll
      for (int e = 0; e < 4; ++e) {
        float ig = acc1[0][e] + bia1[0];
        float fg = acc1[1][e] + bia1[1];
        float gg = acc1[2][e] + bia1[2];
        float og = acc1[3][e] + bia1[3];
        float cn = sigm_(fg) * c1[e] + sigm_(ig) * tanh_(gg);
        c1[e] = cn;
        float hn = sigm_(og) * tanh_(cn);
        h1h[e] = (_Float16)hn;
        out1[(orowbase + (size_t)e * T_ + (t - 1)) * H_ + col] = hn;
      }
#pragma unroll
      for (int e = 0; e < 4; ++e)
        H1[(quad << 2) + e][col] = h1h[e];  // h1(t-1) -> GEMM1(t) after b-mid
    }

    // ---- GEMM0(t): [xb(t)|h0(t-1)] @ W0^T (kb0-3 swizzled LDS, kb4-7 L2 stream)
    f32x4 acc[4] = {};
#pragma unroll
    for (int kb = 0; kb < 8; ++kb) {
      f16x8 a = (kb < 4)
                    ? *(const f16x8*)&XB[l16][(kb << 5) + (quad << 3)]
                    : *(const f16x8*)&H0[cb][l16][((kb - 4) << 5) + (quad << 3)];
      if (kb < 4) {
#pragma unroll
        for (int g = 0; g < 4; ++g) {
          const char* wr = (const char*)W0l + (((g << 7) + col) << 8);
          f16x8 bf = *(const f16x8*)(wr + (((kb << 6) | (quad << 4)) ^ swr));
          acc[g] = MFMA16(a, bf, acc[g]);
        }
      } else {
#pragma unroll
        for (int g = 0; g < 4; ++g) {
          f16x8 bf = *(const f16x8*)(Wpack + (size_t)((g << 7) + col) * KC_ +
                                     (kb << 5) + (quad << 3));
          acc[g] = MFMA16(a, bf, acc[g]);
        }
      }
    }

    // ---- act0(t): register-only; writes to opposite H0 buffer (no barrier needed)
    _Float16 h0h[4];
#pragma unroll
    for (int e = 0; e < 4; ++e) {
      float ig = acc[0][e] + bia0[0];
      float fg = acc[1][e] + bia0[1];
      float gg = acc[2][e] + bia0[2];
      float og = acc[3][e] + bia0[3];
      float cn = sigm_(fg) * c0[e] + sigm_(ig) * tanh_(gg);
      c0[e] = cn;
      h0h[e] = (_Float16)(sigm_(og) * tanh_(cn));
    }
#pragma unroll
    for (int e = 0; e < 4; ++e) {
      H0n[(quad << 2) + e][col] = h0h[e];       // -> GEMM1(t) after b-mid
      H0[cbn][(quad << 2) + e][col] = h0h[e];   // h0(t) -> GEMM0(t+1) after b-end
    }
    __syncthreads();  // b-mid: H0n/H1 ready; all region-A LDS reads complete

    // ---- GEMM1(t): [h0n(t)|h1(t-1)] @ W1^T ; result carried to next region-A
#pragma unroll
    for (int g = 0; g < 4; ++g) acc1[g] = (f32x4){0.f, 0.f, 0.f, 0.f};
#pragma unroll
    for (int kb = 0; kb < 8; ++kb) {
      f16x8 a = (kb < 4)
                    ? *(const f16x8*)&H0n[l16][(kb << 5) + (quad << 3)]
                    : *(const f16x8*)&H1[l16][((kb - 4) << 5) + (quad << 3)];
#pragma unroll
      for (int g = 0; g < 4; ++g) acc1[g] = MFMA16(a, w1[g][kb], acc1[g]);
    }

    if (t + 1 < T_) {  // stage xb(t+1); all XB readers finished before b-mid
      f16x4 hv;
#pragma unroll
      for (int e = 0; e < 4; ++e) hv[e] = (_Float16)fmaf(xn[e], scn[e], shn[e]);
      *(f16x4*)&XB[sr][sc] = hv;
    }
    __syncthreads();  // b-end: XB/H0[cbn] ready for next step
  }

  // ---- epilogue: act1(T-1) + store
  {
#pragma unroll
    for (int e = 0; e < 4; ++e) {
      float ig = acc1[0][e] + bia1[0];
      float fg = acc1[1][e] + bia1[1];
      float gg = acc1[2][e] + bia1[2];
      float og = acc1[3][e] + bia1[3];
      float cn = sigm_(fg) * c1[e] + sigm_(ig) * tanh_(gg);
      float hn = sigm_(og) * tanh_(cn);
      out1[(orowbase + (size_t)e * T_ + (T_ - 1)) * H_ + col] = hn;
    }
  }
}

extern "C" void kernel_launch(void* const* d_in, const int* in_sizes, int n_in,
                              void* d_out, int out_size, void* d_ws, size_t ws_size,
                              hipStream_t stream) {
  const float* X = (const float*)d_in[0];
  const float* attnw = (const float*)d_in[1];
  const float* attnb = (const float*)d_in[2];
  const float* gamma = (const float*)d_in[3];
  const float* beta = (const float*)d_in[4];
  const float* Wih0 = (const float*)d_in[5];
  const float* Whh0 = (const float*)d_in[6];
  const float* bih0 = (const float*)d_in[7];
  const float* bhh0 = (const float*)d_in[8];
  const float* Wih1 = (const float*)d_in[9];
  const float* Whh1 = (const float*)d_in[10];
  const float* bih1 = (const float*)d_in[11];
  const float* bhh1 = (const float*)d_in[12];

  float* out0 = (float*)d_out;                    // X_tilde
  float* out1 = out0 + (size_t)B_ * T_ * N_;      // X_encoded

  // BN partials use out1's region as scratch; consumed by k3r before k4 writes out1.
  float* psum = out1;
  float* psq = out1 + ((size_t)KB2_ << 14);

  float* ws = (float*)d_ws;
  float* scale = ws;                              // T*N
  float* shift = scale + T_ * N_;                 // T*N
  float* bpack = shift + T_ * N_;                 // 2*512
  _Float16* Wpack = (_Float16*)(bpack + 2 * G4_); // 2*512*256 f16 (16B-aligned)

  k0_prep<<<1024, 256, 0, stream>>>(Wih0, Whh0, bih0, bhh0, Wih1, Whh1, bih1, bhh1,
                                    Wpack, bpack);
  k12_fused<<<KB2_, 512, 0, stream>>>(X, attnw, attnb, out0, psum, psq);
  k3r<<<T_, 256, 0, stream>>>(psum, psq, gamma, beta, scale, shift);
  k4_recur<<<NB_, 512, 0, stream>>>(out0, Wpack, bpack, scale, shift, out1);
}

// Round 9
// 1312.656 us; speedup vs baseline: 1.1423x; 1.0325x over previous
//
#include <hip/hip_runtime.h>
#include <cstdint>
#include <cstddef>

#define B_ 4096
#define T_ 128
#define N_ 128
#define H_ 128
#define G4_ 512       // 4*H
#define KC_ 256       // concat K = [x|h]
#define EPS_ 1e-5f

#define RPB_ 16       // batch rows per block (k4)
#define NB_ 256       // k4 blocks (one per CU)
#define W0K_ 128      // layer0 K-half staged in LDS (k = 0..127, the x-part)
#define W0P_ 136      // W0l LDS stride (f16)

#define KB2_ 256      // k12 blocks (one per CU)
#define ROWS2_ 16     // b-rows per k12 block

typedef _Float16 f16x8 __attribute__((ext_vector_type(8)));
typedef _Float16 f16x4 __attribute__((ext_vector_type(4)));
typedef float f32x4 __attribute__((ext_vector_type(4)));

__device__ __forceinline__ float sigm_(float x) { return 1.f / (1.f + __expf(-x)); }
__device__ __forceinline__ float tanh_(float x) {
  float ax = fabsf(x);
  float e = __expf(-2.f * ax);
  float t = (1.f - e) / (1.f + e);
  return copysignf(t, x);
}

#define MFMA16(a, b, c) __builtin_amdgcn_mfma_f32_16x16x32_f16((a), (b), (c), 0, 0, 0)

// ---------------- K0: pack weights to f16 [2][512][256] = [Wih | Whh], combine biases
__global__ void k0_prep(const float* __restrict__ Wih0, const float* __restrict__ Whh0,
                        const float* __restrict__ bih0, const float* __restrict__ bhh0,
                        const float* __restrict__ Wih1, const float* __restrict__ Whh1,
                        const float* __restrict__ bih1, const float* __restrict__ bhh1,
                        _Float16* __restrict__ Wpack, float* __restrict__ bpack) {
  int idx = blockIdx.x * blockDim.x + threadIdx.x;
  if (idx < 2 * G4_ * KC_) {
    int k = idx & (KC_ - 1);
    int j = (idx >> 8) & (G4_ - 1);
    int l = idx >> 17;
    const float* Wih = l ? Wih1 : Wih0;
    const float* Whh = l ? Whh1 : Whh0;
    float v = (k < N_) ? Wih[j * N_ + k] : Whh[j * N_ + (k - N_)];
    Wpack[idx] = (_Float16)v;
  }
  if (idx < 2 * G4_) {
    int j = idx & (G4_ - 1);
    bpack[idx] = (idx >> 9) ? (bih1[j] + bhh1[j]) : (bih0[j] + bhh0[j]);
  }
}

// ---------------- K12: fused alpha + X_tilde + BN partials, double-buffered (round-6, proven)
__global__ __launch_bounds__(512, 1) void k12_fused(
    const float* __restrict__ X, const float* __restrict__ attn_w,
    const float* __restrict__ attn_b, float* __restrict__ out0,
    float* __restrict__ psum, float* __restrict__ psq) {
  __shared__ float xs[2 * T_ * N_];  // 131072 B
  __shared__ float wx[T_];
  __shared__ float redS[4][N_];
  __shared__ float redM[8], redE[8];
  const int tid = threadIdx.x;   // 0..511
  const int blk = blockIdx.x;    // 0..255
  const int n = tid & 127;
  const int tq = tid >> 7;       // t-quarter 0..3
  const int wv = tid >> 6;       // wave 0..7
  const int row0 = blk * ROWS2_;
  if (tid < T_) wx[tid] = attn_w[2 * H_ + tid];
  const float ab = attn_b[0];

  float sum[32], sq[32];
#pragma unroll
  for (int i = 0; i < 32; ++i) { sum[i] = 0.f; sq[i] = 0.f; }

  {
    const float* xb = X + (size_t)row0 * T_ * N_;
#pragma unroll
    for (int i = 0; i < 8; ++i) {
      int fi = ((i << 9) + tid) << 2;
      *(f32x4*)&xs[fi] = *(const f32x4*)&xb[fi];
    }
  }

  int buf = 0;
  for (int rb = 0; rb < ROWS2_; ++rb) {
    __syncthreads();
    const float* xcur = xs + (buf << 14);

    f32x4 stg[8];
    if (rb + 1 < ROWS2_) {
      const float* xb1 = X + (size_t)(row0 + rb + 1) * T_ * N_;
#pragma unroll
      for (int i = 0; i < 8; ++i)
        stg[i] = *(const f32x4*)&xb1[((i << 9) + tid) << 2];
    }

    float s = 0.f;
#pragma unroll
    for (int tt = 0; tt < 32; ++tt) {
      int t = (tq << 5) + tt;
      s = fmaf(xcur[t * N_ + n], wx[t], s);
    }
    redS[tq][n] = s;
    __syncthreads();
    s = redS[0][n] + redS[1][n] + redS[2][n] + redS[3][n] + ab;

    float m = s;
#pragma unroll
    for (int off = 32; off >= 1; off >>= 1) m = fmaxf(m, __shfl_xor(m, off));
    if ((tid & 63) == 0) redM[wv] = m;
    __syncthreads();
    m = fmaxf(fmaxf(fmaxf(redM[0], redM[1]), fmaxf(redM[2], redM[3])),
              fmaxf(fmaxf(redM[4], redM[5]), fmaxf(redM[6], redM[7])));
    float e = __expf(s - m);
    float sm = e;
#pragma unroll
    for (int off = 32; off >= 1; off >>= 1) sm += __shfl_xor(sm, off);
    if ((tid & 63) == 0) redE[wv] = sm;
    __syncthreads();
    sm = redE[0] + redE[1];
    const float alpha = e / sm;

    if (rb + 1 < ROWS2_) {
      float* xnx = xs + ((buf ^ 1) << 14);
#pragma unroll
      for (int i = 0; i < 8; ++i)
        *(f32x4*)&xnx[((i << 9) + tid) << 2] = stg[i];
    }

    const size_t b = (size_t)(row0 + rb);
#pragma unroll
    for (int tt = 0; tt < 32; ++tt) {
      int t = (tq << 5) + tt;
      float v = alpha * xcur[t * N_ + n];
      sum[tt] += v;
      sq[tt] += v * v;
      out0[(b * T_ + t) * N_ + n] = v;
    }
    buf ^= 1;
  }

  float* pbs = psum + ((size_t)blk << 14) + (tq << 5) * N_ + n;
  float* pbq = psq + ((size_t)blk << 14) + (tq << 5) * N_ + n;
#pragma unroll
  for (int tt = 0; tt < 32; ++tt) {
    pbs[tt * N_] = sum[tt];
    pbq[tt * N_] = sq[tt];
  }
}

// ---------------- K3r: reduce partials over 256 blocks -> per-(t,n) scale/shift
__global__ void k3r(const float* __restrict__ psum, const float* __restrict__ psq,
                    const float* __restrict__ gamma, const float* __restrict__ beta,
                    float* __restrict__ scale, float* __restrict__ shift) {
  __shared__ float rs[2][N_], rq[2][N_];
  const int t = blockIdx.x;     // 0..127
  const int tid = threadIdx.x;  // 0..255
  const int n = tid & 127;
  const int hb = tid >> 7;
  const size_t off = (size_t)t * N_ + n;
  float s = 0.f, q = 0.f;
#pragma unroll 4
  for (int i = 0; i < 128; ++i) {
    size_t o = ((size_t)((hb << 7) + i) << 14) + off;
    s += psum[o];
    q += psq[o];
  }
  rs[hb][n] = s;
  rq[hb][n] = q;
  __syncthreads();
  if (hb == 0) {
    s = rs[0][n] + rs[1][n];
    q = rq[0][n] + rq[1][n];
    float mean = s * (1.f / B_);
    float var = q * (1.f / B_) - mean * mean;
    float rstd = rsqrtf(var + EPS_);
    float g = gamma[n];
    scale[t * N_ + n] = rstd * g;
    shift[t * N_ + n] = beta[n] - mean * rstd * g;
  }
}

// ---------------- K4 v10: EXACT v6 structure (proven 737 µs) + asm-pinned w1
// residency. The pin (`asm "+v"`) forbids remat of the 32 weight loads WITHOUT
// volatile's reload-per-use/ordering semantics — GEMM1 becomes pure LDS+MFMA,
// removing 256 KB/block/step (2/3) of the L2 weight stream. Everything else is
// byte-identical to the round-5/6 kernel.
__global__ __launch_bounds__(512, 2) void k4_recur(
    const float* __restrict__ xt /* X_tilde */, const _Float16* __restrict__ Wpack,
    const float* __restrict__ bpack, const float* __restrict__ scale,
    const float* __restrict__ shift, float* __restrict__ out1) {
  __shared__ _Float16 W0l[G4_][W0P_];  // 139264 B
  __shared__ _Float16 A0[RPB_][264];   // [xb | h0], 8448 B
  __shared__ _Float16 A1[RPB_][264];   // [h0n | h1], 8448 B   (total 156160 B)

  const int tid = threadIdx.x;
  const int w = tid >> 6;
  const int lane = tid & 63;
  const int quad = lane >> 4;
  const int l16 = lane & 15;
  const int nb = blockIdx.x;
  const int col = (w << 4) + l16;

  {
    const _Float16* src = Wpack + (size_t)tid * KC_;
#pragma unroll
    for (int kk = 0; kk < W0K_; kk += 8)
      *(f16x8*)&W0l[tid][kk] = *(const f16x8*)&src[kk];
  }

  // layer-1 weights: plain loads, then a one-time register pin. The asm nominally
  // "modifies" each value, so the compiler cannot rematerialize the loads inside
  // the loop; scheduling and combining of the loads themselves remain free.
  f16x8 w1[4][8];
#pragma unroll
  for (int g = 0; g < 4; ++g) {
    const _Float16* src = Wpack + (size_t)(G4_ + (g << 7) + col) * KC_ + (quad << 3);
#pragma unroll
    for (int kb = 0; kb < 8; ++kb) w1[g][kb] = *(const f16x8*)&src[kb << 5];
  }
#pragma unroll
  for (int g = 0; g < 4; ++g)
#pragma unroll
    for (int kb = 0; kb < 8; ++kb)
      asm volatile("" : "+v"(w1[g][kb]));

  float bia0[4], bia1[4];
#pragma unroll
  for (int g = 0; g < 4; ++g) {
    bia0[g] = bpack[(g << 7) + col];
    bia1[g] = bpack[G4_ + (g << 7) + col];
  }

  float c0[4], c1[4];
#pragma unroll
  for (int e = 0; e < 4; ++e) { c0[e] = 0.f; c1[e] = 0.f; }

  const int sr = tid >> 5;
  const int sc = (tid & 31) << 2;
  const size_t browbase = (size_t)(nb * RPB_ + sr) * T_;

  {
    f32x4 xv = *(const f32x4*)(xt + (browbase + 0) * N_ + sc);
    f32x4 s4 = *(const f32x4*)(scale + sc);
    f32x4 h4 = *(const f32x4*)(shift + sc);
    f16x4 hv;
#pragma unroll
    for (int e = 0; e < 4; ++e) hv[e] = (_Float16)fmaf(xv[e], s4[e], h4[e]);
    *(f16x4*)&A0[sr][sc] = hv;
    f16x4 z = {};
    *(f16x4*)&A0[sr][N_ + sc] = z;
    *(f16x4*)&A1[sr][N_ + sc] = z;
  }
  __syncthreads();

  for (int t = 0; t < T_; ++t) {
    f32x4 xn = {};
    if (t + 1 < T_) xn = *(const f32x4*)(xt + (browbase + t + 1) * N_ + sc);

    f32x4 acc[4] = {};
#pragma unroll
    for (int kb = 0; kb < 8; ++kb) {
      f16x8 a = *(const f16x8*)&A0[l16][(kb << 5) + (quad << 3)];
      if (kb < 4) {
#pragma unroll
        for (int g = 0; g < 4; ++g) {
          f16x8 bf = *(const f16x8*)&W0l[(g << 7) + col][(kb << 5) + (quad << 3)];
          acc[g] = MFMA16(a, bf, acc[g]);
        }
      } else {
#pragma unroll
        for (int g = 0; g < 4; ++g) {
          f16x8 bf = *(const f16x8*)(Wpack + (size_t)((g << 7) + col) * KC_ +
                                     (kb << 5) + (quad << 3));
          acc[g] = MFMA16(a, bf, acc[g]);
        }
      }
    }

    _Float16 h0h[4];
#pragma unroll
    for (int e = 0; e < 4; ++e) {
      float ig = acc[0][e] + bia0[0];
      float fg = acc[1][e] + bia0[1];
      float gg = acc[2][e] + bia0[2];
      float og = acc[3][e] + bia0[3];
      float cn = sigm_(fg) * c0[e] + sigm_(ig) * tanh_(gg);
      c0[e] = cn;
      h0h[e] = (_Float16)(sigm_(og) * tanh_(cn));
    }
    __syncthreads();  // #1
#pragma unroll
    for (int e = 0; e < 4; ++e) {
      A0[(quad << 2) + e][N_ + col] = h0h[e];
      A1[(quad << 2) + e][col] = h0h[e];
    }
    __syncthreads();  // #2

    f16x8 a1[8];
#pragma unroll
    for (int kb = 0; kb < 4; ++kb) {
      a1[kb] = *(const f16x8*)&A1[l16][(kb << 5) + (quad << 3)];
      a1[4 + kb] = *(const f16x8*)&A1[l16][128 + (kb << 5) + (quad << 3)];
    }
    f32x4 acc1[4] = {};
#pragma unroll
    for (int kb = 0; kb < 8; ++kb) {
#pragma unroll
      for (int g = 0; g < 4; ++g)
        acc1[g] = MFMA16(a1[kb], w1[g][kb], acc1[g]);
    }

    _Float16 h1h[4];
#pragma unroll
    for (int e = 0; e < 4; ++e) {
      float ig = acc1[0][e] + bia1[0];
      float fg = acc1[1][e] + bia1[1];
      float gg = acc1[2][e] + bia1[2];
      float og = acc1[3][e] + bia1[3];
      float cn = sigm_(fg) * c1[e] + sigm_(ig) * tanh_(gg);
      c1[e] = cn;
      float hn = sigm_(og) * tanh_(cn);
      h1h[e] = (_Float16)hn;
      out1[((size_t)(nb * RPB_ + (quad << 2) + e) * T_ + t) * H_ + col] = hn;
    }
    __syncthreads();  // #3
#pragma unroll
    for (int e = 0; e < 4; ++e)
      A1[(quad << 2) + e][N_ + col] = h1h[e];
    if (t + 1 < T_) {
      f32x4 s4 = *(const f32x4*)(scale + (t + 1) * N_ + sc);
      f32x4 h4 = *(const f32x4*)(shift + (t + 1) * N_ + sc);
      f16x4 hv;
#pragma unroll
      for (int e = 0; e < 4; ++e) hv[e] = (_Float16)fmaf(xn[e], s4[e], h4[e]);
      *(f16x4*)&A0[sr][sc] = hv;
    }
    __syncthreads();  // #4
  }
}

extern "C" void kernel_launch(void* const* d_in, const int* in_sizes, int n_in,
                              void* d_out, int out_size, void* d_ws, size_t ws_size,
                              hipStream_t stream) {
  const float* X = (const float*)d_in[0];
  const float* attnw = (const float*)d_in[1];
  const float* attnb = (const float*)d_in[2];
  const float* gamma = (const float*)d_in[3];
  const float* beta = (const float*)d_in[4];
  const float* Wih0 = (const float*)d_in[5];
  const float* Whh0 = (const float*)d_in[6];
  const float* bih0 = (const float*)d_in[7];
  const float* bhh0 = (const float*)d_in[8];
  const float* Wih1 = (const float*)d_in[9];
  const float* Whh1 = (const float*)d_in[10];
  const float* bih1 = (const float*)d_in[11];
  const float* bhh1 = (const float*)d_in[12];

  float* out0 = (float*)d_out;                    // X_tilde
  float* out1 = out0 + (size_t)B_ * T_ * N_;      // X_encoded

  // BN partials use out1's region as scratch; consumed by k3r before k4 writes out1.
  float* psum = out1;
  float* psq = out1 + ((size_t)KB2_ << 14);

  float* ws = (float*)d_ws;
  float* scale = ws;                              // T*N
  float* shift = scale + T_ * N_;                 // T*N
  float* bpack = shift + T_ * N_;                 // 2*512
  _Float16* Wpack = (_Float16*)(bpack + 2 * G4_); // 2*512*256 f16 (16B-aligned)

  k0_prep<<<1024, 256, 0, stream>>>(Wih0, Whh0, bih0, bhh0, Wih1, Whh1, bih1, bhh1,
                                    Wpack, bpack);
  k12_fused<<<KB2_, 512, 0, stream>>>(X, attnw, attnb, out0, psum, psq);
  k3r<<<T_, 256, 0, stream>>>(psum, psq, gamma, beta, scale, shift);
  k4_recur<<<NB_, 512, 0, stream>>>(out0, Wpack, bpack, scale, shift, out1);
}